// Round 2
// baseline (548.821 us; speedup 1.0000x reference)
//
#include <hip/hip_runtime.h>

#define N_NODES 50000
#define N_EDGES 800000
#define D 64          // D_IN == D_OUT
#define ED 32         // EDGE_DIM
#define BN_EPS 1e-5f

#define SCAN_THREADS 1024
#define CHUNK 49      // ceil(N_NODES / SCAN_THREADS)

// Workspace layout (float indices). memset covers [0, WS_OFF) only.
#define WS_SUMS   0
#define WS_SUMSQ  64
#define WS_SCALE  128
#define WS_SHIFT  192
#define WS_DEG    256
#define WS_OFF    (WS_DEG + N_NODES)          // 50256
#define WS_CURSOR (WS_OFF + N_NODES + 4)      // 100260 (pad keeps alignment)
#define WS_SORTED (WS_CURSOR + N_NODES)       // 150260 — int2[E], 8B/16B aligned
#define WS_H      (WS_SORTED + 2 * N_EDGES)   // 1750260
// total: 1750260 + 3200000 = 4950260 floats ~= 19.8 MB

// ---------------------------------------------------------------------------
// Stage 1a: degree histogram (int atomics only)
__global__ __launch_bounds__(256) void count_kernel(
    const int* __restrict__ dst, int* __restrict__ deg)
{
    int i = blockIdx.x * 256 + threadIdx.x;
    const int stride = gridDim.x * 256;
    for (; i < N_EDGES / 4; i += stride) {
        int4 d = ((const int4*)dst)[i];
        atomicAdd(&deg[d.x], 1);
        atomicAdd(&deg[d.y], 1);
        atomicAdd(&deg[d.z], 1);
        atomicAdd(&deg[d.w], 1);
    }
}

// ---------------------------------------------------------------------------
// Stage 1b: exclusive prefix sum over deg -> off, cursor (single block)
__global__ __launch_bounds__(SCAN_THREADS) void scan_kernel(
    const int* __restrict__ deg, int* __restrict__ off, int* __restrict__ cursor)
{
    __shared__ int sP[SCAN_THREADS];
    const int t = threadIdx.x;
    const int base = t * CHUNK;
    int cnt = N_NODES - base;
    cnt = cnt < 0 ? 0 : (cnt > CHUNK ? CHUNK : cnt);
    int s = 0;
    for (int j = 0; j < cnt; ++j) s += deg[base + j];
    sP[t] = s;
    __syncthreads();
    for (int o = 1; o < SCAN_THREADS; o <<= 1) {   // Hillis-Steele inclusive
        int v = sP[t];
        int add = (t >= o) ? sP[t - o] : 0;
        __syncthreads();
        sP[t] = v + add;
        __syncthreads();
    }
    int run = (t > 0) ? sP[t - 1] : 0;             // exclusive for this chunk
    for (int j = 0; j < cnt; ++j) {
        int d = deg[base + j];
        off[base + j] = run;
        cursor[base + j] = run;
        run += d;
    }
    if (t == 0) off[N_NODES] = N_EDGES;
}

// ---------------------------------------------------------------------------
// Stage 1c: counting-sort scatter of (edge_id, src) by dst
__global__ __launch_bounds__(256) void scatter_kernel(
    const int* __restrict__ ei, int* __restrict__ cursor, int2* __restrict__ sorted)
{
    int i = blockIdx.x * 256 + threadIdx.x;
    const int stride = gridDim.x * 256;
    for (; i < N_EDGES; i += stride) {
        const int src = ei[i];
        const int dst = ei[N_EDGES + i];
        const int pos = atomicAdd(&cursor[dst], 1);
        sorted[pos] = make_int2(i, src);
    }
}

// ---------------------------------------------------------------------------
// Stage 2: per-node aggregation (no f32 atomics) fused with MLP layer 1 + BN stats.
// One wave per node, lane = feature. agg = sumX + (sumEA)@We + deg*be; h=(agg+x)@W1+b1.
__global__ __launch_bounds__(256) void agg_mlp1_kernel(
    const float* __restrict__ x, const float* __restrict__ ea,
    const float* __restrict__ We, const float* __restrict__ be,
    const float* __restrict__ W1, const float* __restrict__ b1,
    const int* __restrict__ off, const int2* __restrict__ sorted,
    float* __restrict__ h, float* __restrict__ sums, float* __restrict__ sumsq)
{
    __shared__ float sWe[ED][D];     // 8 KB   (read sWe[k][f], f stride-1: 2-way, free)
    __shared__ float sW1[D][D];      // 16 KB
    __shared__ float sRed[2][4][D];  // 2 KB block reduction

    const int tid = threadIdx.x;
    for (int i = tid; i < ED * D; i += 256) sWe[i >> 6][i & 63] = We[i];
    for (int i = tid; i < D * D; i += 256) sW1[i >> 6][i & 63] = W1[i];
    const int f = tid & 63;
    const int w = tid >> 6;
    const float be_f = be[f];
    const float b1_f = b1[f];
    float psum = 0.f, psq = 0.f;
    __syncthreads();

    const int gstride = gridDim.x * 4;
    for (int node0 = blockIdx.x * 4; node0 < N_NODES; node0 += gstride) {
        const int node = node0 + w;     // wave-uniform; block-uniform loop bound
        if (node < N_NODES) {
            const int start = off[node], end = off[node + 1];
            float sumX = 0.f, accEA = 0.f;
            int2 es = (start < end) ? sorted[start] : make_int2(0, 0);
            for (int j = start; j < end; ++j) {
                int2 nes = (j + 1 < end) ? sorted[j + 1] : es;  // prefetch
                sumX += x[(size_t)es.y * D + f];
                if (f < ED) accEA += ea[(size_t)es.x * ED + f];
                es = nes;
            }
            float val = sumX + x[(size_t)node * D + f] + (float)(end - start) * be_f;
            #pragma unroll
            for (int k = 0; k < ED; ++k) val += __shfl(accEA, k) * sWe[k][f];
            float hacc = b1_f;
            #pragma unroll
            for (int k = 0; k < D; ++k) hacc += __shfl(val, k) * sW1[k][f];
            h[(size_t)node * D + f] = hacc;
            psum += hacc;
            psq += hacc * hacc;
        }
    }
    sRed[0][w][f] = psum;
    sRed[1][w][f] = psq;
    __syncthreads();
    if (w == 0) {
        const float s = sRed[0][0][f] + sRed[0][1][f] + sRed[0][2][f] + sRed[0][3][f];
        const float q = sRed[1][0][f] + sRed[1][1][f] + sRed[1][2][f] + sRed[1][3][f];
        unsafeAtomicAdd(&sums[f], s);
        unsafeAtomicAdd(&sumsq[f], q);
    }
}

// ---------------------------------------------------------------------------
// Stage 3: finalize BN stats into per-feature scale/shift.
__global__ void stats_kernel(
    const float* __restrict__ sums, const float* __restrict__ sumsq,
    const float* __restrict__ gamma, const float* __restrict__ beta,
    float* __restrict__ scale, float* __restrict__ shift)
{
    const int f = threadIdx.x;  // 64 threads
    const float inv_n = 1.0f / (float)N_NODES;
    const float mean = sums[f] * inv_n;
    const float var  = sumsq[f] * inv_n - mean * mean;  // biased, like jnp.var
    const float sc   = gamma[f] * rsqrtf(var + BN_EPS);
    scale[f] = sc;
    shift[f] = beta[f] - mean * sc;
}

// ---------------------------------------------------------------------------
// Stage 4: out = relu(h*scale + shift) @ W2 + b2, one wave per node.
__global__ __launch_bounds__(256) void mlp2_kernel(
    const float* __restrict__ h, const float* __restrict__ W2,
    const float* __restrict__ b2, const float* __restrict__ scale,
    const float* __restrict__ shift, float* __restrict__ out)
{
    __shared__ float sW2[D][D];  // 16 KB
    const int tid = threadIdx.x;
    for (int i = tid; i < D * D; i += 256) sW2[i >> 6][i & 63] = W2[i];
    const int f = tid & 63;
    const int w = tid >> 6;
    const float sc = scale[f], sh = shift[f], b = b2[f];
    __syncthreads();

    const int gstride = gridDim.x * 4;
    for (int node0 = blockIdx.x * 4; node0 < N_NODES; node0 += gstride) {
        const int node = node0 + w;
        if (node < N_NODES) {
            float v = h[(size_t)node * D + f] * sc + sh;
            v = v > 0.f ? v : 0.f;
            float acc = b;
            #pragma unroll
            for (int k = 0; k < D; ++k) acc += __shfl(v, k) * sW2[k][f];
            out[(size_t)node * D + f] = acc;
        }
    }
}

// ---------------------------------------------------------------------------
extern "C" void kernel_launch(void* const* d_in, const int* in_sizes, int n_in,
                              void* d_out, int out_size, void* d_ws, size_t ws_size,
                              hipStream_t stream) {
    const float* x     = (const float*)d_in[0];
    const int*   ei    = (const int*)  d_in[1];   // [2, E] int32
    const float* ea    = (const float*)d_in[2];
    const float* We    = (const float*)d_in[3];
    const float* be    = (const float*)d_in[4];
    const float* W1    = (const float*)d_in[5];
    const float* b1    = (const float*)d_in[6];
    const float* gamma = (const float*)d_in[7];
    const float* beta  = (const float*)d_in[8];
    const float* W2    = (const float*)d_in[9];
    const float* b2    = (const float*)d_in[10];

    float* ws     = (float*)d_ws;
    float* sums   = ws + WS_SUMS;
    float* sumsq  = ws + WS_SUMSQ;
    float* scale  = ws + WS_SCALE;
    float* shift  = ws + WS_SHIFT;
    int*   deg    = (int*)(ws + WS_DEG);
    int*   off    = (int*)(ws + WS_OFF);
    int*   cursor = (int*)(ws + WS_CURSOR);
    int2*  sorted = (int2*)(ws + WS_SORTED);
    float* h      = ws + WS_H;

    // zero stats + deg only (~201 KB)
    hipMemsetAsync(ws, 0, (size_t)WS_OFF * sizeof(float), stream);

    count_kernel  <<<784, 256, 0, stream>>>(ei + N_EDGES, deg);
    scan_kernel   <<<1, SCAN_THREADS, 0, stream>>>(deg, off, cursor);
    scatter_kernel<<<1024, 256, 0, stream>>>(ei, cursor, sorted);
    agg_mlp1_kernel<<<1536, 256, 0, stream>>>(x, ea, We, be, W1, b1, off, sorted,
                                              h, sums, sumsq);
    stats_kernel  <<<1, 64, 0, stream>>>(sums, sumsq, gamma, beta, scale, shift);
    mlp2_kernel   <<<1024, 256, 0, stream>>>(h, W2, b2, scale, shift, (float*)d_out);
}

// Round 3
// 444.464 us; speedup vs baseline: 1.2348x; 1.2348x over previous
//
#include <hip/hip_runtime.h>

#define N_NODES 50000
#define N_EDGES 800000
#define D 64          // D_IN == D_OUT
#define ED 32         // EDGE_DIM
#define BN_EPS 1e-5f

// Workspace layout (float/int indices). memset covers [0, WS_OFF).
#define WS_SUMS    0
#define WS_SUMSQ   64
#define WS_SCALE   128
#define WS_SHIFT   192
#define WS_PART    256                       // 64 ints (block partial sums)
#define WS_PARTPRE 320                       // 64 ints (exclusive prefix of partials)
#define WS_DEG     384
#define WS_OFF     (WS_DEG + N_NODES)        // 50384  (16B aligned)
#define WS_CURSOR  (WS_OFF + N_NODES + 4)    // 100388 (16B aligned)
#define WS_SORTED  (WS_CURSOR + N_NODES)     // 150388 — int2[E]
#define WS_H       (WS_SORTED + 2 * N_EDGES) // 1750388
// total: 1750388 + 3200000 floats ~= 19.8 MB

#define SCAN_BLOCKS 50   // 50 x 1000 elements = N_NODES exactly

// ---------------------------------------------------------------------------
// Stage 1a: degree histogram (int atomics only)
__global__ __launch_bounds__(256) void count_kernel(
    const int* __restrict__ dst, int* __restrict__ deg)
{
    int i = blockIdx.x * 256 + threadIdx.x;
    const int stride = gridDim.x * 256;
    for (; i < N_EDGES / 4; i += stride) {
        int4 d = ((const int4*)dst)[i];
        atomicAdd(&deg[d.x], 1);
        atomicAdd(&deg[d.y], 1);
        atomicAdd(&deg[d.z], 1);
        atomicAdd(&deg[d.w], 1);
    }
}

// ---------------------------------------------------------------------------
// Stage 1b-1: per-block partial sums over 1000 ints each (coalesced int4)
__global__ __launch_bounds__(256) void scan_partial_kernel(
    const int* __restrict__ deg, int* __restrict__ partial)
{
    __shared__ int sR[256];
    const int t = threadIdx.x;
    const int base = blockIdx.x * 1000;
    int local = 0;
    if (t < 250) {
        int4 d = ((const int4*)(deg + base))[t];
        local = d.x + d.y + d.z + d.w;
    }
    sR[t] = local;
    __syncthreads();
    for (int o = 128; o > 0; o >>= 1) {
        if (t < o) sR[t] += sR[t + o];
        __syncthreads();
    }
    if (t == 0) partial[blockIdx.x] = sR[0];
}

// Stage 1b-2: exclusive scan of the 50 partials (one wave)
__global__ __launch_bounds__(64) void scan_top_kernel(
    const int* __restrict__ partial, int* __restrict__ partialPre)
{
    const int t = threadIdx.x;
    int v = (t < SCAN_BLOCKS) ? partial[t] : 0;
    int inc = v;
    for (int o = 1; o < 64; o <<= 1) {
        int u = __shfl_up(inc, o);
        if (t >= o) inc += u;
    }
    if (t < SCAN_BLOCKS) partialPre[t] = inc - v;
}

// Stage 1b-3: block-local scan + global offset; write off & cursor (int4)
__global__ __launch_bounds__(256) void scan_write_kernel(
    const int* __restrict__ deg, const int* __restrict__ partialPre,
    int* __restrict__ off, int* __restrict__ cursor)
{
    __shared__ int sS[256];
    const int t = threadIdx.x;
    const int base = blockIdx.x * 1000;
    int4 d = make_int4(0, 0, 0, 0);
    int local = 0;
    if (t < 250) {
        d = ((const int4*)(deg + base))[t];
        local = d.x + d.y + d.z + d.w;
    }
    sS[t] = local;
    __syncthreads();
    for (int o = 1; o < 256; o <<= 1) {
        int v = sS[t];
        int add = (t >= o) ? sS[t - o] : 0;
        __syncthreads();
        sS[t] = v + add;
        __syncthreads();
    }
    if (t < 250) {
        int p = partialPre[blockIdx.x] + sS[t] - local;  // exclusive prefix
        int4 o4 = make_int4(p, p + d.x, p + d.x + d.y, p + d.x + d.y + d.z);
        ((int4*)(off + base))[t] = o4;
        ((int4*)(cursor + base))[t] = o4;
    }
    if (blockIdx.x == 0 && t == 0) off[N_NODES] = N_EDGES;
}

// ---------------------------------------------------------------------------
// Stage 1c: counting-sort scatter of (edge_id, src) by dst
__global__ __launch_bounds__(256) void scatter_kernel(
    const int* __restrict__ ei, int* __restrict__ cursor, int2* __restrict__ sorted)
{
    int i = blockIdx.x * 256 + threadIdx.x;
    const int stride = gridDim.x * 256;
    for (; i < N_EDGES; i += stride) {
        const int src = ei[i];
        const int dst = ei[N_EDGES + i];
        const int pos = atomicAdd(&cursor[dst], 1);
        sorted[pos] = make_int2(i, src);
    }
}

// ---------------------------------------------------------------------------
// Stage 2: per-node aggregation fused with MLP layer 1 + BN stats.
// One wave per node, lane = feature. agg = sumX + (sumEA)@We + deg*be;
// h = (agg + x)@W1 + b1. Edge loop unrolled 4x + pipelined; ea gathers use
// the full wave (lanes 0-31: even edges, 32-63: odd edges).
__global__ __launch_bounds__(256) void agg_mlp1_kernel(
    const float* __restrict__ x, const float* __restrict__ ea,
    const float* __restrict__ We, const float* __restrict__ be,
    const float* __restrict__ W1, const float* __restrict__ b1,
    const int* __restrict__ off, const int2* __restrict__ sorted,
    float* __restrict__ h, float* __restrict__ sums, float* __restrict__ sumsq)
{
    __shared__ float sWe[ED][D];     // 8 KB
    __shared__ float sW1[D][D];      // 16 KB
    __shared__ float sRed[2][4][D];  // 2 KB

    const int tid = threadIdx.x;
    for (int i = tid; i < ED * D; i += 256) sWe[i >> 6][i & 63] = We[i];
    for (int i = tid; i < D * D; i += 256) sW1[i >> 6][i & 63] = W1[i];
    const int f = tid & 63;
    const int w = tid >> 6;
    const int fe = f & 31;
    const bool lo = (f < 32);
    const float be_f = be[f];
    const float b1_f = b1[f];
    float psum = 0.f, psq = 0.f;
    __syncthreads();

    const int gstride = gridDim.x * 4;
    for (int node0 = blockIdx.x * 4; node0 < N_NODES; node0 += gstride) {
        const int node = node0 + w;     // wave-uniform
        if (node < N_NODES) {
            const int start = off[node], end = off[node + 1];
            float s0 = 0.f, s1 = 0.f, s2 = 0.f, s3 = 0.f;
            float a0 = 0.f, a1 = 0.f;
            int j = start;
            int2 c0, c1, c2, c3;
            if (j + 4 <= end) {
                c0 = sorted[j]; c1 = sorted[j + 1];
                c2 = sorted[j + 2]; c3 = sorted[j + 3];
            }
            // pipelined 4x unrolled body: next indices load while current gathers
            for (; j + 8 <= end; j += 4) {
                int2 n0 = sorted[j + 4], n1 = sorted[j + 5];
                int2 n2 = sorted[j + 6], n3 = sorted[j + 7];
                s0 += x[(size_t)c0.y * D + f];
                s1 += x[(size_t)c1.y * D + f];
                s2 += x[(size_t)c2.y * D + f];
                s3 += x[(size_t)c3.y * D + f];
                a0 += ea[(size_t)(lo ? c0.x : c1.x) * ED + fe];
                a1 += ea[(size_t)(lo ? c2.x : c3.x) * ED + fe];
                c0 = n0; c1 = n1; c2 = n2; c3 = n3;
            }
            if (j + 4 <= end) {
                s0 += x[(size_t)c0.y * D + f];
                s1 += x[(size_t)c1.y * D + f];
                s2 += x[(size_t)c2.y * D + f];
                s3 += x[(size_t)c3.y * D + f];
                a0 += ea[(size_t)(lo ? c0.x : c1.x) * ED + fe];
                a1 += ea[(size_t)(lo ? c2.x : c3.x) * ED + fe];
                j += 4;
            }
            for (; j < end; ++j) {          // tail (low half accumulates ea)
                int2 p = sorted[j];
                s0 += x[(size_t)p.y * D + f];
                if (lo) a0 += ea[(size_t)p.x * ED + fe];
            }
            const float accEA = a0 + a1;
            float val = (s0 + s1) + (s2 + s3) + x[(size_t)node * D + f]
                      + (float)(end - start) * be_f;
            #pragma unroll
            for (int k = 0; k < ED; ++k)
                val += (__shfl(accEA, k) + __shfl(accEA, k + 32)) * sWe[k][f];
            float hacc = b1_f;
            #pragma unroll
            for (int k = 0; k < D; ++k) hacc += __shfl(val, k) * sW1[k][f];
            h[(size_t)node * D + f] = hacc;
            psum += hacc;
            psq += hacc * hacc;
        }
    }
    sRed[0][w][f] = psum;
    sRed[1][w][f] = psq;
    __syncthreads();
    if (w == 0) {
        const float s = sRed[0][0][f] + sRed[0][1][f] + sRed[0][2][f] + sRed[0][3][f];
        const float q = sRed[1][0][f] + sRed[1][1][f] + sRed[1][2][f] + sRed[1][3][f];
        unsafeAtomicAdd(&sums[f], s);
        unsafeAtomicAdd(&sumsq[f], q);
    }
}

// ---------------------------------------------------------------------------
// Stage 3: finalize BN stats into per-feature scale/shift.
__global__ void stats_kernel(
    const float* __restrict__ sums, const float* __restrict__ sumsq,
    const float* __restrict__ gamma, const float* __restrict__ beta,
    float* __restrict__ scale, float* __restrict__ shift)
{
    const int f = threadIdx.x;  // 64 threads
    const float inv_n = 1.0f / (float)N_NODES;
    const float mean = sums[f] * inv_n;
    const float var  = sumsq[f] * inv_n - mean * mean;  // biased, like jnp.var
    const float sc   = gamma[f] * rsqrtf(var + BN_EPS);
    scale[f] = sc;
    shift[f] = beta[f] - mean * sc;
}

// ---------------------------------------------------------------------------
// Stage 4: out = relu(h*scale + shift) @ W2 + b2, one wave per node.
__global__ __launch_bounds__(256) void mlp2_kernel(
    const float* __restrict__ h, const float* __restrict__ W2,
    const float* __restrict__ b2, const float* __restrict__ scale,
    const float* __restrict__ shift, float* __restrict__ out)
{
    __shared__ float sW2[D][D];  // 16 KB
    const int tid = threadIdx.x;
    for (int i = tid; i < D * D; i += 256) sW2[i >> 6][i & 63] = W2[i];
    const int f = tid & 63;
    const int w = tid >> 6;
    const float sc = scale[f], sh = shift[f], b = b2[f];
    __syncthreads();

    const int gstride = gridDim.x * 4;
    for (int node0 = blockIdx.x * 4; node0 < N_NODES; node0 += gstride) {
        const int node = node0 + w;
        if (node < N_NODES) {
            float v = h[(size_t)node * D + f] * sc + sh;
            v = v > 0.f ? v : 0.f;
            float acc = b;
            #pragma unroll
            for (int k = 0; k < D; ++k) acc += __shfl(v, k) * sW2[k][f];
            out[(size_t)node * D + f] = acc;
        }
    }
}

// ---------------------------------------------------------------------------
extern "C" void kernel_launch(void* const* d_in, const int* in_sizes, int n_in,
                              void* d_out, int out_size, void* d_ws, size_t ws_size,
                              hipStream_t stream) {
    const float* x     = (const float*)d_in[0];
    const int*   ei    = (const int*)  d_in[1];   // [2, E] int32
    const float* ea    = (const float*)d_in[2];
    const float* We    = (const float*)d_in[3];
    const float* be    = (const float*)d_in[4];
    const float* W1    = (const float*)d_in[5];
    const float* b1    = (const float*)d_in[6];
    const float* gamma = (const float*)d_in[7];
    const float* beta  = (const float*)d_in[8];
    const float* W2    = (const float*)d_in[9];
    const float* b2    = (const float*)d_in[10];

    float* ws      = (float*)d_ws;
    float* sums    = ws + WS_SUMS;
    float* sumsq   = ws + WS_SUMSQ;
    float* scale   = ws + WS_SCALE;
    float* shift   = ws + WS_SHIFT;
    int*   partial = (int*)(ws + WS_PART);
    int*   partPre = (int*)(ws + WS_PARTPRE);
    int*   deg     = (int*)(ws + WS_DEG);
    int*   off     = (int*)(ws + WS_OFF);
    int*   cursor  = (int*)(ws + WS_CURSOR);
    int2*  sorted  = (int2*)(ws + WS_SORTED);
    float* h       = ws + WS_H;

    // zero stats + deg (~201 KB)
    hipMemsetAsync(ws, 0, (size_t)WS_OFF * sizeof(float), stream);

    count_kernel      <<<784, 256, 0, stream>>>(ei + N_EDGES, deg);
    scan_partial_kernel<<<SCAN_BLOCKS, 256, 0, stream>>>(deg, partial);
    scan_top_kernel   <<<1, 64, 0, stream>>>(partial, partPre);
    scan_write_kernel <<<SCAN_BLOCKS, 256, 0, stream>>>(deg, partPre, off, cursor);
    scatter_kernel    <<<1024, 256, 0, stream>>>(ei, cursor, sorted);
    agg_mlp1_kernel   <<<1536, 256, 0, stream>>>(x, ea, We, be, W1, b1, off, sorted,
                                                 h, sums, sumsq);
    stats_kernel      <<<1, 64, 0, stream>>>(sums, sumsq, gamma, beta, scale, shift);
    mlp2_kernel       <<<1024, 256, 0, stream>>>(h, W2, b2, scale, shift, (float*)d_out);
}

// Round 4
// 405.070 us; speedup vs baseline: 1.3549x; 1.0973x over previous
//
#include <hip/hip_runtime.h>

#define N_NODES 50000
#define N_EDGES 800000
#define D 64          // D_IN == D_OUT
#define ED 32         // EDGE_DIM
#define BN_EPS 1e-5f

// ---- workspace layout (32-bit word indices) -------------------------------
#define WS_SUMS     0
#define WS_SUMSQ    64
#define WS_PART     128                       // 64 ints: scan partials
#define WS_DEG      256
#define WS_ZERO_END (WS_DEG + N_NODES)        // memset [0, here)  (~201 KB)
#define WS_OFF      (WS_DEG + N_NODES)        // 50256  (byte 201024, 16B ok)
#define WS_CURSOR   (WS_OFF + N_NODES + 4)    // 100260 (byte 401040, 16B ok)
#define WS_SRC      (WS_CURSOR + N_NODES)     // 150260
// fast path (needs ~68 MB):
#define WS_EAB      (WS_SRC + N_EDGES)        // 950260 (byte 3801040, 16B ok)
#define WS_H_FAST   (WS_EAB + 16 * N_EDGES)   // 13750260
#define WS_FAST_WORDS (WS_H_FAST + N_NODES * D)
// fallback path (R3 structure, ~20 MB): sorted int2 (eid,src) at WS_SRC
#define WS_H_SLOW   (WS_SRC + 2 * N_EDGES)    // 1750260

#define SCAN_BLOCKS 50   // 50 x 1000 = N_NODES exactly

__device__ __forceinline__ unsigned int bf16r(float f) {
    unsigned int u = __float_as_uint(f);
    return (u + 0x7fffu + ((u >> 16) & 1u)) >> 16;     // round-to-nearest-even
}
__device__ __forceinline__ unsigned int pack2(float lo, float hi) {
    return bf16r(lo) | (bf16r(hi) << 16);
}

// ---------------------------------------------------------------------------
// degree histogram (int atomics)
__global__ __launch_bounds__(256) void count_kernel(
    const int* __restrict__ dst, int* __restrict__ deg)
{
    int i = blockIdx.x * 256 + threadIdx.x;
    const int stride = gridDim.x * 256;
    for (; i < N_EDGES / 4; i += stride) {
        int4 d = ((const int4*)dst)[i];
        atomicAdd(&deg[d.x], 1);
        atomicAdd(&deg[d.y], 1);
        atomicAdd(&deg[d.z], 1);
        atomicAdd(&deg[d.w], 1);
    }
}

// per-block partial sums over 1000 ints (coalesced int4)
__global__ __launch_bounds__(256) void scan_partial_kernel(
    const int* __restrict__ deg, int* __restrict__ partial)
{
    __shared__ int sR[256];
    const int t = threadIdx.x;
    const int base = blockIdx.x * 1000;
    int local = 0;
    if (t < 250) {
        int4 d = ((const int4*)(deg + base))[t];
        local = d.x + d.y + d.z + d.w;
    }
    sR[t] = local;
    __syncthreads();
    for (int o = 128; o > 0; o >>= 1) {
        if (t < o) sR[t] += sR[t + o];
        __syncthreads();
    }
    if (t == 0) partial[blockIdx.x] = sR[0];
}

// block-local scan + in-kernel top scan of the 50 partials; writes off & cursor
__global__ __launch_bounds__(256) void scan_write_kernel(
    const int* __restrict__ deg, const int* __restrict__ partial,
    int* __restrict__ off, int* __restrict__ cursor)
{
    __shared__ int sS[256];
    __shared__ int sTop;
    const int t = threadIdx.x;
    if (t < 64) {                       // wave 0: exclusive scan of partials
        int v = (t < SCAN_BLOCKS) ? partial[t] : 0;
        int inc = v;
        for (int o = 1; o < 64; o <<= 1) {
            int u = __shfl_up(inc, o);
            if (t >= o) inc += u;
        }
        if (t == blockIdx.x) sTop = inc - v;
    }
    const int base = blockIdx.x * 1000;
    int4 d = make_int4(0, 0, 0, 0);
    int local = 0;
    if (t < 250) {
        d = ((const int4*)(deg + base))[t];
        local = d.x + d.y + d.z + d.w;
    }
    sS[t] = local;
    __syncthreads();
    for (int o = 1; o < 256; o <<= 1) {
        int v = sS[t];
        int add = (t >= o) ? sS[t - o] : 0;
        __syncthreads();
        sS[t] = v + add;
        __syncthreads();
    }
    if (t < 250) {
        int p = sTop + sS[t] - local;   // exclusive prefix
        int4 o4 = make_int4(p, p + d.x, p + d.x + d.y, p + d.x + d.y + d.z);
        ((int4*)(off + base))[t] = o4;
        ((int4*)(cursor + base))[t] = o4;
    }
    if (blockIdx.x == 0 && t == 0) off[N_NODES] = N_EDGES;
}

// ---------------------------------------------------------------------------
// FAST: permute ea (f32, edge order, sequential) -> bf16x2 rows in dst-sorted
// order (random 64B writes, fire-and-forget). 8 lanes per edge; E%8==0.
__global__ __launch_bounds__(256) void permute_kernel(
    const int* __restrict__ ei, const float* __restrict__ ea,
    int* __restrict__ cursor, int* __restrict__ sorted_src,
    unsigned int* __restrict__ eab)
{
    const int tid = threadIdx.x;
    const int lane = tid & 63;
    const int g = lane >> 3, sub = lane & 7;
    const int wv = blockIdx.x * 4 + (tid >> 6);
    const int nwv = gridDim.x * 4;
    for (int e0 = wv * 8; e0 < N_EDGES; e0 += nwv * 8) {
        const int e = e0 + g;
        const float4 v = ((const float4*)ea)[(size_t)e * 8 + sub];  // 1KB/wave seq
        int pos = 0;
        if (sub == 0) {
            const int src = ei[e];
            const int dst = ei[N_EDGES + e];
            pos = atomicAdd(&cursor[dst], 1);
            sorted_src[pos] = src;
        }
        pos = __shfl(pos, g * 8);
        uint2 p;
        p.x = pack2(v.x, v.y);          // uint j holds features (2j, 2j+1)
        p.y = pack2(v.z, v.w);
        ((uint2*)eab)[(size_t)pos * 8 + sub] = p;   // 64B row, random
    }
}

// FAST: per-node aggregation (sequential bf16 ea + x gathers) + MLP1 + BN stats
__global__ __launch_bounds__(256) void agg_mlp1_fast(
    const float* __restrict__ x, const unsigned int* __restrict__ eab,
    const float* __restrict__ We, const float* __restrict__ be,
    const float* __restrict__ W1, const float* __restrict__ b1,
    const int* __restrict__ off, const int* __restrict__ sorted_src,
    float* __restrict__ h, float* __restrict__ sums, float* __restrict__ sumsq)
{
    __shared__ float sWe[ED][D];     // 8 KB
    __shared__ float sW1[D][D];      // 16 KB
    __shared__ float sRed[2][4][D];  // 2 KB

    const int tid = threadIdx.x;
    for (int i = tid; i < ED * D; i += 256) sWe[i >> 6][i & 63] = We[i];
    for (int i = tid; i < D * D; i += 256) sW1[i >> 6][i & 63] = W1[i];
    const int f = tid & 63;
    const int w = tid >> 6;
    const float be_f = be[f], b1_f = b1[f];
    float psum = 0.f, psq = 0.f;
    __syncthreads();

    const int gstride = gridDim.x * 4;
    for (int node0 = blockIdx.x * 4; node0 < N_NODES; node0 += gstride) {
        const int node = node0 + w;    // wave-uniform
        if (node < N_NODES) {
            const int start = off[node], end = off[node + 1];
            const int n = end - start;
            const int* sp = sorted_src + start;
            const unsigned int* ep = eab + (size_t)start * 16;
            float s0 = 0.f, s1 = 0.f, s2 = 0.f, s3 = 0.f, eax = 0.f, eay = 0.f;
            int it = 0;
            int a0 = 0, a1 = 0, a2 = 0, a3 = 0;
            unsigned int ue = 0;
            if (n >= 4) {
                a0 = sp[0]; a1 = sp[1]; a2 = sp[2]; a3 = sp[3];
                ue = ep[f];                    // rows 0..3: lane covers row f>>4, pair f&15
            }
            for (; it + 8 <= n; it += 4) {     // pipelined: next group loads early
                const int n0 = sp[it + 4], n1 = sp[it + 5];
                const int n2 = sp[it + 6], n3 = sp[it + 7];
                const unsigned int un = ep[(it + 4) * 16 + f];
                s0 += x[(size_t)a0 * D + f];
                s1 += x[(size_t)a1 * D + f];
                s2 += x[(size_t)a2 * D + f];
                s3 += x[(size_t)a3 * D + f];
                eax += __uint_as_float(ue << 16);
                eay += __uint_as_float(ue & 0xffff0000u);
                a0 = n0; a1 = n1; a2 = n2; a3 = n3; ue = un;
            }
            if (it + 4 <= n) {
                s0 += x[(size_t)a0 * D + f];
                s1 += x[(size_t)a1 * D + f];
                s2 += x[(size_t)a2 * D + f];
                s3 += x[(size_t)a3 * D + f];
                eax += __uint_as_float(ue << 16);
                eay += __uint_as_float(ue & 0xffff0000u);
                it += 4;
            }
            if (it < n) {                      // tail: 1..3 rows
                if ((f >> 4) < (n - it)) {
                    const unsigned int ut = ep[it * 16 + f];
                    eax += __uint_as_float(ut << 16);
                    eay += __uint_as_float(ut & 0xffff0000u);
                }
                for (; it < n; ++it) s0 += x[(size_t)sp[it] * D + f];
            }
            // combine the 4 row-groups: every lane gets pair-sum for (f&15)
            eax += __shfl_xor(eax, 16); eax += __shfl_xor(eax, 32);
            eay += __shfl_xor(eay, 16); eay += __shfl_xor(eay, 32);
            float val = (s0 + s1) + (s2 + s3) + x[(size_t)node * D + f]
                      + (float)n * be_f;
            #pragma unroll
            for (int k = 0; k < ED; ++k) {
                const float a = (k & 1) ? eay : eax;   // lane k>>1 holds pair k>>1
                val += __shfl(a, k >> 1) * sWe[k][f];
            }
            float hacc = b1_f;
            #pragma unroll
            for (int k = 0; k < D; ++k) hacc += __shfl(val, k) * sW1[k][f];
            h[(size_t)node * D + f] = hacc;
            psum += hacc;
            psq += hacc * hacc;
        }
    }
    sRed[0][w][f] = psum;
    sRed[1][w][f] = psq;
    __syncthreads();
    if (w == 0) {
        const float s = sRed[0][0][f] + sRed[0][1][f] + sRed[0][2][f] + sRed[0][3][f];
        const float q = sRed[1][0][f] + sRed[1][1][f] + sRed[1][2][f] + sRed[1][3][f];
        unsafeAtomicAdd(&sums[f], s);
        unsafeAtomicAdd(&sumsq[f], q);
    }
}

// ---------------------------------------------------------------------------
// FALLBACK (ws too small): R3 structure — sorted int2 (eid,src), f32 ea gather
__global__ __launch_bounds__(256) void scatter_kernel(
    const int* __restrict__ ei, int* __restrict__ cursor, int2* __restrict__ sorted)
{
    int i = blockIdx.x * 256 + threadIdx.x;
    const int stride = gridDim.x * 256;
    for (; i < N_EDGES; i += stride) {
        const int src = ei[i];
        const int dst = ei[N_EDGES + i];
        const int pos = atomicAdd(&cursor[dst], 1);
        sorted[pos] = make_int2(i, src);
    }
}

__global__ __launch_bounds__(256) void agg_mlp1_slow(
    const float* __restrict__ x, const float* __restrict__ ea,
    const float* __restrict__ We, const float* __restrict__ be,
    const float* __restrict__ W1, const float* __restrict__ b1,
    const int* __restrict__ off, const int2* __restrict__ sorted,
    float* __restrict__ h, float* __restrict__ sums, float* __restrict__ sumsq)
{
    __shared__ float sWe[ED][D];
    __shared__ float sW1[D][D];
    __shared__ float sRed[2][4][D];

    const int tid = threadIdx.x;
    for (int i = tid; i < ED * D; i += 256) sWe[i >> 6][i & 63] = We[i];
    for (int i = tid; i < D * D; i += 256) sW1[i >> 6][i & 63] = W1[i];
    const int f = tid & 63;
    const int w = tid >> 6;
    const int fe = f & 31;
    const bool lo = (f < 32);
    const float be_f = be[f], b1_f = b1[f];
    float psum = 0.f, psq = 0.f;
    __syncthreads();

    const int gstride = gridDim.x * 4;
    for (int node0 = blockIdx.x * 4; node0 < N_NODES; node0 += gstride) {
        const int node = node0 + w;
        if (node < N_NODES) {
            const int start = off[node], end = off[node + 1];
            float s0 = 0.f, s1 = 0.f, s2 = 0.f, s3 = 0.f, ax = 0.f, ay = 0.f;
            int j = start;
            int2 c0, c1, c2, c3;
            if (j + 4 <= end) {
                c0 = sorted[j]; c1 = sorted[j + 1];
                c2 = sorted[j + 2]; c3 = sorted[j + 3];
            }
            for (; j + 8 <= end; j += 4) {
                int2 n0 = sorted[j + 4], n1 = sorted[j + 5];
                int2 n2 = sorted[j + 6], n3 = sorted[j + 7];
                s0 += x[(size_t)c0.y * D + f];
                s1 += x[(size_t)c1.y * D + f];
                s2 += x[(size_t)c2.y * D + f];
                s3 += x[(size_t)c3.y * D + f];
                ax += ea[(size_t)(lo ? c0.x : c1.x) * ED + fe];
                ay += ea[(size_t)(lo ? c2.x : c3.x) * ED + fe];
                c0 = n0; c1 = n1; c2 = n2; c3 = n3;
            }
            if (j + 4 <= end) {
                s0 += x[(size_t)c0.y * D + f];
                s1 += x[(size_t)c1.y * D + f];
                s2 += x[(size_t)c2.y * D + f];
                s3 += x[(size_t)c3.y * D + f];
                ax += ea[(size_t)(lo ? c0.x : c1.x) * ED + fe];
                ay += ea[(size_t)(lo ? c2.x : c3.x) * ED + fe];
                j += 4;
            }
            for (; j < end; ++j) {
                int2 p = sorted[j];
                s0 += x[(size_t)p.y * D + f];
                if (lo) ax += ea[(size_t)p.x * ED + fe];
            }
            const float accEA = ax + ay;
            float val = (s0 + s1) + (s2 + s3) + x[(size_t)node * D + f]
                      + (float)(end - start) * be_f;
            #pragma unroll
            for (int k = 0; k < ED; ++k)
                val += (__shfl(accEA, k) + __shfl(accEA, k + 32)) * sWe[k][f];
            float hacc = b1_f;
            #pragma unroll
            for (int k = 0; k < D; ++k) hacc += __shfl(val, k) * sW1[k][f];
            h[(size_t)node * D + f] = hacc;
            psum += hacc;
            psq += hacc * hacc;
        }
    }
    sRed[0][w][f] = psum;
    sRed[1][w][f] = psq;
    __syncthreads();
    if (w == 0) {
        const float s = sRed[0][0][f] + sRed[0][1][f] + sRed[0][2][f] + sRed[0][3][f];
        const float q = sRed[1][0][f] + sRed[1][1][f] + sRed[1][2][f] + sRed[1][3][f];
        unsafeAtomicAdd(&sums[f], s);
        unsafeAtomicAdd(&sumsq[f], q);
    }
}

// ---------------------------------------------------------------------------
// MLP2 with BN stats finalized inline per block: out = relu(h*sc+sh) @ W2 + b2
__global__ __launch_bounds__(256) void mlp2_kernel(
    const float* __restrict__ h, const float* __restrict__ W2,
    const float* __restrict__ b2, const float* __restrict__ sums,
    const float* __restrict__ sumsq, const float* __restrict__ gamma,
    const float* __restrict__ beta, float* __restrict__ out)
{
    __shared__ float sW2[D][D];  // 16 KB
    const int tid = threadIdx.x;
    for (int i = tid; i < D * D; i += 256) sW2[i >> 6][i & 63] = W2[i];
    const int f = tid & 63;
    const int w = tid >> 6;
    const float inv_n = 1.0f / (float)N_NODES;
    const float mean = sums[f] * inv_n;
    const float var  = sumsq[f] * inv_n - mean * mean;   // biased, like jnp.var
    const float sc   = gamma[f] * rsqrtf(var + BN_EPS);
    const float sh   = beta[f] - mean * sc;
    const float b    = b2[f];
    __syncthreads();

    const int gstride = gridDim.x * 4;
    for (int node0 = blockIdx.x * 4; node0 < N_NODES; node0 += gstride) {
        const int node = node0 + w;
        if (node < N_NODES) {
            float v = h[(size_t)node * D + f] * sc + sh;
            v = v > 0.f ? v : 0.f;
            float acc = b;
            #pragma unroll
            for (int k = 0; k < D; ++k) acc += __shfl(v, k) * sW2[k][f];
            out[(size_t)node * D + f] = acc;
        }
    }
}

// ---------------------------------------------------------------------------
extern "C" void kernel_launch(void* const* d_in, const int* in_sizes, int n_in,
                              void* d_out, int out_size, void* d_ws, size_t ws_size,
                              hipStream_t stream) {
    const float* x     = (const float*)d_in[0];
    const int*   ei    = (const int*)  d_in[1];   // [2, E] int32
    const float* ea    = (const float*)d_in[2];
    const float* We    = (const float*)d_in[3];
    const float* be    = (const float*)d_in[4];
    const float* W1    = (const float*)d_in[5];
    const float* b1    = (const float*)d_in[6];
    const float* gamma = (const float*)d_in[7];
    const float* beta  = (const float*)d_in[8];
    const float* W2    = (const float*)d_in[9];
    const float* b2    = (const float*)d_in[10];

    float* ws       = (float*)d_ws;
    float* sums     = ws + WS_SUMS;
    float* sumsq    = ws + WS_SUMSQ;
    int*   partial  = (int*)(ws + WS_PART);
    int*   deg      = (int*)(ws + WS_DEG);
    int*   off      = (int*)(ws + WS_OFF);
    int*   cursor   = (int*)(ws + WS_CURSOR);
    int*   ssrc     = (int*)(ws + WS_SRC);
    unsigned int* eab = (unsigned int*)(ws + WS_EAB);
    int2*  sorted2  = (int2*)(ws + WS_SRC);

    const bool fast = ws_size >= (size_t)WS_FAST_WORDS * sizeof(float);
    float* h = ws + (fast ? WS_H_FAST : WS_H_SLOW);

    hipMemsetAsync(ws, 0, (size_t)WS_ZERO_END * sizeof(float), stream);

    count_kernel       <<<784, 256, 0, stream>>>(ei + N_EDGES, deg);
    scan_partial_kernel<<<SCAN_BLOCKS, 256, 0, stream>>>(deg, partial);
    scan_write_kernel  <<<SCAN_BLOCKS, 256, 0, stream>>>(deg, partial, off, cursor);
    if (fast) {
        permute_kernel <<<2048, 256, 0, stream>>>(ei, ea, cursor, ssrc, eab);
        agg_mlp1_fast  <<<1536, 256, 0, stream>>>(x, eab, We, be, W1, b1, off, ssrc,
                                                  h, sums, sumsq);
    } else {
        scatter_kernel <<<1024, 256, 0, stream>>>(ei, cursor, sorted2);
        agg_mlp1_slow  <<<1536, 256, 0, stream>>>(x, ea, We, be, W1, b1, off, sorted2,
                                                  h, sums, sumsq);
    }
    mlp2_kernel        <<<1024, 256, 0, stream>>>(h, W2, b2, sums, sumsq,
                                                  gamma, beta, (float*)d_out);
}